// Round 16
// baseline (438.648 us; speedup 1.0000x reference)
//
#include <hip/hip_runtime.h>
#include <stdint.h>

// Match numpy reference bit-exactly on the IoU path: no fma contraction.
#pragma clang fp contract(off)

#define BF 4
#define NN 4096
#define MAXC 16
#define PL 2048   // per-label partition capacity
#define WL 32     // PL/64 words per partition row
#define WF 24     // full-LDS leader-pass capacity (Vl<=1536; +15.7 sigma)
#define TRI_CAP (64 * (WL * (WL + 1) / 2))  // per-fl packed triangle capacity (u64)

typedef unsigned long long u64;
typedef uint32_t u32;

#define WAVE_SYNC() asm volatile("s_waitcnt lgkmcnt(0)" ::: "memory")

__device__ __forceinline__ u64 shfl64(u64 v, int src) {
  return (u64)__shfl((long long)v, src, 64);
}
__device__ __forceinline__ u64 readlane64(u64 v, int l) {
  u32 lo = (u32)__builtin_amdgcn_readlane((int)(u32)v, l);
  u32 hi = (u32)__builtin_amdgcn_readlane((int)(u32)(v >> 32), l);
  return ((u64)hi << 32) | lo;
}
// Greedy with ISO bulk-accept (R11, verified).
__device__ __forceinline__ u64 greedy64_iso(u64 D, u64 rem, u64 onlyme) {
  u64 lead = 0;
  while (rem) {
    u64 t = D & rem;
    u64 iso = __ballot(t == onlyme) & rem;
    lead |= iso;
    rem &= ~iso;
    if (!rem) break;
    int b = __builtin_ctzll(rem);
    lead |= 1ull << b;
    rem &= ~readlane64(D, b);
    if (!rem) break;
    b = __builtin_ctzll(rem);
    lead |= 1ull << b;
    rem &= ~readlane64(D, b);
  }
  return lead;
}
// Clamp Vl to sane range at every phase entry (defense in depth).
__device__ __forceinline__ int loadVl(const int* VbufL, int fl) {
  int v = VbufL[fl];
  return (v < 0) ? 0 : ((v > PL) ? PL : v);
}

// One-shot grid barrier #k. SAFE co-residency: 156KB static LDS forces
// 1 block/CU; grid=256=#CUs => all blocks resident before any completes.
// clock64 failsafe turns a (theoretically impossible) deadlock into a
// wrong-answer instead of a hang.
__device__ __forceinline__ void gbar(int* bar, int k) {
  __syncthreads();
  __threadfence();                          // release
  if (threadIdx.x == 0) {
    atomicAdd(&bar[k], 1);                  // device scope by default
    long long t0 = clock64();
    while (__hip_atomic_load(&bar[k], __ATOMIC_RELAXED,
                             __HIP_MEMORY_SCOPE_AGENT) < (int)gridDim.x) {
      __builtin_amdgcn_s_sleep(2);
      if (clock64() - t0 > (3LL << 30)) break;  // ~1.3 s failsafe
    }
  }
  __syncthreads();
  __threadfence();                          // acquire
}

struct Prm {
  const float* scores; const float* boxes; const int* labels;
  const float* W1; const float* b1; const float* W2; const float* b2;
  float* sboxes; float* sscore; float* slabel;
  int* lab_slot; int* loc_slot; int* pglob;
  float* px1; float* px2; float* py1; float* py2; float* parea;
  int* VbufL; u64* leadersP; int* cidP; u64* maskP; u64* triT;
  int* bar;
  float* out;
};

// ---------------------------------------------------------------------------
// Single kernel, 5 phases, manual grid barriers. 256 blocks x 256 threads,
// 156KB LDS arena (1 block/CU, exactly co-resident).
// R16 FIX: phase-1 arena carve was wrong by 4x (256 ints = 128 u64, not 32):
// cnt/lcnt/vc overlapped -> garbage VbufL/pglob -> OOB faults (R14/R15 abort).
// ---------------------------------------------------------------------------
__global__ __launch_bounds__(256, 1) void fused_kernel(Prm pr)
{
  __shared__ u64 SM[19500];                 // 156,000 B arena
  const int tid = threadIdx.x, wave = tid >> 6, lane = tid & 63;
  const u64 ltmask = (1ull << lane) - 1ull;

  // ===== phase 1: fused rank + partition-loc + gather (R13) =====
  {
    u64* keys = SM;                         // [0, 4096) u64
    int* cnt  = (int*)&SM[4096];            // [4096, 4224): 256 ints = 128 u64
    int* lcnt = (int*)&SM[4224];            // [4224, 4352): 256 ints = 128 u64
    int* vc   = (int*)&SM[4352];            // [4352, 4354): 12 ints
    const int f = blockIdx.x >> 6, rb = blockIdx.x & 63;
    for (int s = 0; s < 16; s++) {
      int idx = tid + 256 * s;
      float sc = pr.scores[f * NN + idx];
      bool valid = sc > 0.2f;               // COND_THRES
      int lab = pr.labels[f * NN + idx];
      u32 bits = __float_as_uint(sc);
      u32 m = bits ^ ((bits >> 31) ? 0xFFFFFFFFu : 0x80000000u);
      u32 hi = valid ? ~m : 0xFFFFFFFFu;    // smaller = higher score
      u32 lo = ((u32)idx << 2) | (valid ? (u32)lab : 3u);
      keys[idx] = ((u64)hi << 32) | lo;
    }
    __syncthreads();
    if (rb == 0) {                          // per-label totals
      int c0 = 0, c1 = 0, c2 = 0;
      const int base = wave * 1024;
      for (int s = 0; s < 16; s++) {
        u32 lb = (u32)keys[base + s * 64 + lane] & 3u;
        c0 += (lb == 0); c1 += (lb == 1); c2 += (lb == 2);
      }
      for (int off = 32; off; off >>= 1) {
        c0 += __shfl_xor(c0, off, 64);
        c1 += __shfl_xor(c1, off, 64);
        c2 += __shfl_xor(c2, off, 64);
      }
      if (lane == 0) { vc[wave * 3 + 0] = c0; vc[wave * 3 + 1] = c1; vc[wave * 3 + 2] = c2; }
    }
    const int row = rb * 64 + lane;
    const u64 mykey = keys[row];
    const u32 mylab = (u32)mykey & 3u;
    int c = 0, lc = 0;
    const int j0 = wave * 1024;
#pragma unroll 8
    for (int j = j0; j < j0 + 1024; j++) {
      u64 kj = keys[j];                     // broadcast LDS read
      bool lt = kj < mykey;
      c += lt ? 1 : 0;
      lc += (lt && (((u32)kj & 3u) == mylab)) ? 1 : 0;
    }
    cnt[wave * 64 + lane] = c;
    lcnt[wave * 64 + lane] = lc;
    __syncthreads();
    if (rb == 0 && wave == 1 && lane < 3)
      pr.VbufL[f * 3 + lane] = vc[0 * 3 + lane] + vc[1 * 3 + lane]
                             + vc[2 * 3 + lane] + vc[3 * 3 + lane];
    if (wave == 0) {                        // gather + scatter tail
      int rank = cnt[lane] + cnt[64 + lane] + cnt[128 + lane] + cnt[192 + lane];
      int loc  = lcnt[lane] + lcnt[64 + lane] + lcnt[128 + lane] + lcnt[192 + lane];
      const int i = row;
      const float* bp = pr.boxes + (size_t)(f * NN + i) * 7;
      float b0 = bp[0], b1v = bp[1], b2v = bp[2], b3 = bp[3], b4 = bp[4], b5 = bp[5], b6 = bp[6];
      int lab = pr.labels[f * NN + i];
      float sc = pr.scores[f * NN + i];
      const int o = f * NN + rank;
      float* sb = pr.sboxes + (size_t)o * 7;
      sb[0] = b0; sb[1] = b1v; sb[2] = b2v; sb[3] = b3; sb[4] = b4; sb[5] = b5; sb[6] = b6;
      pr.sscore[o] = sc;
      pr.slabel[o] = (float)lab;
      if (mylab < 3u) {
        int pi = (f * 3 + (int)mylab) * PL + loc;
        float off = (float)mylab * 10000.0f;  // CLASS_OFFSET
        float cx = b0 + off, cy = b1v;
        float hx = b3 * 0.5f, hy = b4 * 0.5f;
        float x1 = cx - hx, x2 = cx + hx, y1 = cy - hy, y2 = cy + hy;
        float area = (x2 - x1) * (y2 - y1);
        pr.pglob[pi] = rank;
        pr.px1[pi] = x1; pr.px2[pi] = x2; pr.py1[pi] = y1; pr.py2[pi] = y2;
        pr.parea[pi] = area;
        pr.lab_slot[o] = (int)mylab; pr.loc_slot[o] = loc;
      } else {
        pr.lab_slot[o] = -1; pr.loc_slot[o] = -1;
      }
    }
  }
  gbar(pr.bar, 0);

  // ===== phase 2: overlap bitmask (grid-stride tiles) =====
  {
    float4* cbox = (float4*)SM;             // [0,2048) u64
    float*  carea = (float*)&SM[2048];      // [2048,2560) u64
    for (int vt = blockIdx.x; vt < BF * 3 * 256; vt += 256) {
      __syncthreads();                      // LDS safe vs previous tile
      const int fl = vt >> 8, rem = vt & 255;
      const int rt = rem >> 1, wt = rem & 1;
      const int r0 = rt * 16;
      const int Vl = loadVl(pr.VbufL, fl);
      const bool act = (r0 < Vl) && (wt * 1024 < Vl);
      if (act) {
        const int ncol = Vl - wt * 1024;
        const int nload = (ncol < 1024) ? ncol : 1024;
        for (int q = tid; q < nload; q += 256) {
          int cc = fl * PL + wt * 1024 + q;
          cbox[q] = make_float4(pr.px1[cc], pr.px2[cc], pr.py1[cc], pr.py2[cc]);
          carea[q] = pr.parea[cc];
        }
      }
      __syncthreads();
      if (!act) continue;
      const int row = r0 + (tid & 15);
      const int wl = tid >> 4;
      const int cw = wt * 16 + wl;
      const int nc = Vl - cw * 64;
      if (row < Vl && nc > 0) {
        const int rg = fl * PL + row;
        const float rx1 = pr.px1[rg], rx2 = pr.px2[rg];
        const float ry1 = pr.py1[rg], ry2 = pr.py2[rg], ra = pr.parea[rg];
        u64 bits = 0;
        const int qb = wl * 64;
        for (int b = 0; b < 64; b++) {
          float4 cb = cbox[qb + b];
          float ca = carea[qb + b];
          float ix = fminf(rx2, cb.y) - fmaxf(rx1, cb.x);
          ix = fmaxf(ix, 0.0f);
          float iy = fminf(ry2, cb.w) - fmaxf(ry1, cb.z);
          iy = fmaxf(iy, 0.0f);
          float inter = ix * iy;
          float den = fmaxf((ra + ca) - inter, 1e-6f);
          float iou = inter / den;
          bits |= ((u64)(iou > 0.3f)) << b; // IOU_THRES
        }
        if (nc < 64) bits &= (1ull << nc) - 1ull;
        const int f = fl / 3;
        const int p = pr.pglob[fl * PL + row] & (NN - 1);  // clamp (defense)
        pr.maskP[((size_t)f * NN + p) * WL + cw] = bits;
        if (row >= 64 * cw) {               // packed lower triangle
          const int W = (Vl + 63) >> 6;
          int base = 64 * (cw * W - (cw * (cw - 1)) / 2);
          pr.triT[(size_t)fl * TRI_CAP + base + (row - 64 * cw)] = bits;
        }
      }
    }
  }
  gbar(pr.bar, 1);

  // ===== phase 3: leader pass (blocks 0..11, wave 0 only) =====
  if (blockIdx.x < BF * 3 && wave == 0) {
    u64* tri = SM;
    const int fl = blockIdx.x;
    const int Vl = loadVl(pr.VbufL, fl);
    const int W = (Vl + 63) >> 6;           // <= WL = 32
    const u64* mT = pr.triT + (size_t)fl * TRI_CAP;
    const u64 onlyme = 1ull << lane;
    u64 alive = 0;
    if (lane < WL) {
      int rb2 = Vl - 64 * lane;
      alive = (rb2 >= 64) ? ~0ull : ((rb2 > 0) ? ((1ull << rb2) - 1ull) : 0ull);
    }
    u64 myLead = 0;
    if (W > 0 && W <= WF) {
      const int totw = 64 * (W * (W + 1) / 2);
      const int nch = (totw * 8 + 1023) >> 10;
      const char* g = (const char*)mT;
      char* l = (char*)tri;
      int batch = 0;
      for (int it = 0; it < nch; it++) {
        __builtin_amdgcn_global_load_lds(
            (const __attribute__((address_space(1))) unsigned int*)(g + (size_t)it * 1024 + (size_t)lane * 16),
            (__attribute__((address_space(3))) unsigned int*)(l + (size_t)it * 1024),
            16, 0, 0);
        if (++batch == 48) {
          asm volatile("s_waitcnt vmcnt(0)" ::: "memory");
          batch = 0;
        }
      }
      asm volatile("s_waitcnt vmcnt(0)" ::: "memory");
      int offw = 0;
      u64 D = tri[lane];
      for (int w = 0; w < W; w++) {
        const int offw_next = offw + 64 * (W - w);
        u64 Dnext = (w + 1 < W) ? tri[offw_next + lane] : 0;
        u64 lead = greedy64_iso(D, readlane64(alive, w), onlyme);
        if (lane == w) myLead = lead;
        if (lead) {
          const u64* strm = tri + offw;
          int v = w + 1;
          for (; v + 3 < W; v += 4) {
            u64 a0 = strm[64 * (v - w) + lane];
            u64 a1 = strm[64 * (v + 1 - w) + lane];
            u64 a2 = strm[64 * (v + 2 - w) + lane];
            u64 a3 = strm[64 * (v + 3 - w) + lane];
            u64 c0 = __ballot((a0 & lead) != 0ull);
            u64 c1 = __ballot((a1 & lead) != 0ull);
            u64 c2 = __ballot((a2 & lead) != 0ull);
            u64 c3 = __ballot((a3 & lead) != 0ull);
            if (lane == v)     alive &= ~c0;
            if (lane == v + 1) alive &= ~c1;
            if (lane == v + 2) alive &= ~c2;
            if (lane == v + 3) alive &= ~c3;
          }
          for (; v < W; v++) {
            u64 a0 = strm[64 * (v - w) + lane];
            u64 c0 = __ballot((a0 & lead) != 0ull);
            if (lane == v) alive &= ~c0;
          }
        }
        D = Dnext;
        offw = offw_next;
      }
    } else if (W > 0) {                     // fallback (W in (WF, WL])
      int offw = 0;
      for (int w = 0; w < W; w++) {
        const u64* strm = mT + offw;
        u64 D = strm[lane];
        u64 lead = greedy64_iso(D, readlane64(alive, w), onlyme);
        if (lane == w) myLead = lead;
        if (lead) {
          for (int v = w + 1; v < W; v++) {
            u64 a0 = strm[64 * (v - w) + lane];
            u64 c0 = __ballot((a0 & lead) != 0ull);
            if (lane == v) alive &= ~c0;
          }
        }
        offw += 64 * (W - w);
      }
    }
    if (lane < WL) pr.leadersP[fl * WL + lane] = myLead;
  }
  gbar(pr.bar, 2);

  // ===== phase 4: cid (grid-stride waves) =====
  for (int g = blockIdx.x * 4 + wave; g < BF * NN; g += 1024) {
    const int f = g >> 12, p = g & (NN - 1);
    const int l = pr.lab_slot[f * NN + p];
    if (l < 0) continue;
    const int fl = f * 3 + l;
    const int loc = pr.loc_slot[f * NN + p];
    const int Wl = (loadVl(pr.VbufL, fl) + 63) >> 6;
    u64 L = 0, m = 0;
    if (lane < Wl) {
      L = pr.leadersP[fl * WL + lane];
      m = pr.maskP[((size_t)f * NN + p) * WL + lane];
    }
    const int g6 = loc >> 6, b6 = loc & 63;
    u64 pmask = (lane < g6) ? ~0ull
              : (lane == g6 ? ((b6 == 63) ? ~0ull : ((1ull << (b6 + 1)) - 1ull)) : 0ull);
    u64 v = m & L & pmask;
    u64 bl = __ballot(v != 0ull);
    int cid = -1;
    if (bl != 0ull) {
      int w = __builtin_ctzll(bl);
      u64 vw = shfl64(v, w);
      cid = w * 64 + __builtin_ctzll(vw);
    }
    if (lane == 0) pr.cidP[fl * PL + loc] = cid;
  }
  gbar(pr.bar, 3);

  // ===== phase 5: members + merge (grid-stride waves, per-wave LDS) =====
  {
    u64* base = &SM[wave * 80];             // 80 u64 per wave, disjoint
    int*   mlist = (int*)base;              // [0,8): 16 ints
    float* mbv   = (float*)(base + 8);      // [8,64): mb[s*7+d], 112 floats
    float* lg    = (float*)(base + 64);     // [64,72): 16 floats
    float* wn    = (float*)(base + 72);     // [72,80): 16 floats
    float w1r[7];
    for (int d = 0; d < 7; d++) w1r[d] = pr.W1[d * 64 + lane];
    const float b1c = pr.b1[lane], w2c = pr.W2[lane], b2v = pr.b2[0];
    for (int g = blockIdx.x * 4 + wave; g < BF * NN; g += 1024) {
      const int f = g >> 12, i = g & (NN - 1);
      const int o = f * NN + i;
      float* info = pr.out + (size_t)o * 9;
      float* lead = pr.out + (size_t)BF * NN * 9 + o;
      const int l = pr.lab_slot[o];
      bool isLead = false;
      int loc = 0, fl = 0;
      if (l >= 0) {
        fl = f * 3 + l;
        loc = pr.loc_slot[o];
        isLead = (pr.leadersP[fl * WL + (loc >> 6)] >> (loc & 63)) & 1ull;
      }
      if (!isLead) {
        if (lane < 9) info[lane] = 0.0f;
        if (lane == 0) *lead = 0.0f;
        continue;
      }
      const u64* mrow = pr.maskP + (size_t)o * WL;
      const int Wl = (loadVl(pr.VbufL, fl) + 63) >> 6;
      int total = 0;
      for (int w = loc >> 6; w < Wl && total < MAXC; w++) {
        u64 word = mrow[w];
        int pos = w * 64 + lane;
        bool cand = ((word >> lane) & 1ull) && (pr.cidP[fl * PL + pos] == loc);
        u64 mbal = __ballot(cand);
        int r = __popcll(mbal & ltmask);
        int slot = total + r;
        if (cand && slot < MAXC) mlist[slot] = pr.pglob[fl * PL + pos];
        total += __popcll(mbal);
      }
      const int cnt = min(total, MAXC);
      WAVE_SYNC();
      if (lane < cnt) {
        int j = mlist[lane] & (NN - 1);     // clamp (defense)
        const float* bp = pr.sboxes + (size_t)(f * NN + j) * 7;
        for (int d = 0; d < 7; d++) mbv[lane * 7 + d] = bp[d];
      }
      WAVE_SYNC();
      for (int s = 0; s < cnt; s++) {
        float t = b1c;
        for (int d = 0; d < 7; d++) t += mbv[s * 7 + d] * w1r[d];
        float h = fmaxf(t, 0.0f);
        float v = h * w2c;
        for (int off2 = 32; off2 > 0; off2 >>= 1) v += __shfl_xor(v, off2, 64);
        if (lane == 0) lg[s] = v + b2v;
      }
      WAVE_SYNC();
      float mx = -1e30f;
      for (int s = 0; s < cnt; s++) mx = fmaxf(mx, lg[s]);
      float den = 0.0f;
      for (int s = 0; s < cnt; s++) den += expf(lg[s] - mx);
      if (lane < cnt) wn[lane] = expf(lg[lane] - mx) / den;
      WAVE_SYNC();
      float val = 0.0f;
      if (lane < 7) {
        float acc = 0.0f;
        for (int s = 0; s < cnt; s++) acc += wn[s] * mbv[s * 7 + lane];
        val = acc;
        if (lane >= 3 && lane <= 5 && val <= 0.0f) val = pr.sboxes[(size_t)o * 7 + lane];
      } else if (lane == 7) {
        val = pr.sscore[o];
      } else if (lane == 8) {
        val = pr.slabel[o];
      }
      if (lane < 9) info[lane] = val;
      if (lane == 0) *lead = 1.0f;
      WAVE_SYNC();                          // LDS safe vs next iteration
    }
  }
}

// ---------------------------------------------------------------------------
extern "C" void kernel_launch(void* const* d_in, const int* in_sizes, int n_in,
                              void* d_out, int out_size, void* d_ws, size_t ws_size,
                              hipStream_t stream)
{
  char* ws = (char*)d_ws;
  size_t off = 0;
  auto alloc = [&](size_t bytes) -> void* {
    void* p = ws + off;
    off = (off + bytes + 255) & ~(size_t)255;
    return p;
  };
  Prm pr;
  pr.scores = (const float*)d_in[1];
  pr.boxes  = (const float*)d_in[0];
  pr.labels = (const int*)d_in[2];
  pr.W1 = (const float*)d_in[3];
  pr.b1 = (const float*)d_in[4];
  pr.W2 = (const float*)d_in[5];
  pr.b2 = (const float*)d_in[6];
  pr.out = (float*)d_out;
  pr.bar     = (int*)  alloc(256);          // 4 barrier counters (zeroed below)
  pr.sboxes  = (float*)alloc((size_t)BF * NN * 7 * 4);
  pr.sscore  = (float*)alloc((size_t)BF * NN * 4);
  pr.slabel  = (float*)alloc((size_t)BF * NN * 4);
  pr.lab_slot= (int*)  alloc((size_t)BF * NN * 4);
  pr.loc_slot= (int*)  alloc((size_t)BF * NN * 4);
  pr.pglob   = (int*)  alloc((size_t)BF * 3 * PL * 4);
  pr.px1     = (float*)alloc((size_t)BF * 3 * PL * 4);
  pr.px2     = (float*)alloc((size_t)BF * 3 * PL * 4);
  pr.py1     = (float*)alloc((size_t)BF * 3 * PL * 4);
  pr.py2     = (float*)alloc((size_t)BF * 3 * PL * 4);
  pr.parea   = (float*)alloc((size_t)BF * 3 * PL * 4);
  pr.VbufL   = (int*)  alloc((size_t)BF * 3 * 4);
  pr.leadersP= (u64*)  alloc((size_t)BF * 3 * WL * 8);
  pr.cidP    = (int*)  alloc((size_t)BF * 3 * PL * 4);
  pr.maskP   = (u64*)  alloc((size_t)BF * NN * WL * 8);        // 4 MB
  pr.triT    = (u64*)  alloc((size_t)BF * 3 * TRI_CAP * 8);    // 3.2 MB
  (void)      alloc(32768);                 // DMA overrun slack after triT

  hipMemsetAsync(pr.bar, 0, 256, stream);   // zero barrier counters (d_ws is
                                            // poisoned 0xAA before each call)
  fused_kernel<<<dim3(256), dim3(256), 0, stream>>>(pr);
}

// Round 17
// 212.153 us; speedup vs baseline: 2.0676x; 2.0676x over previous
//
#include <hip/hip_runtime.h>
#include <stdint.h>

// Match numpy reference bit-exactly on the IoU path: no fma contraction.
#pragma clang fp contract(off)

#define BF 4
#define NN 4096
#define MAXC 16
#define PL 2048   // per-label partition capacity
#define WL 32     // PL/64 words per partition row
#define WF 24     // full-LDS leader-pass capacity (Vl<=1536; +15.7 sigma)
#define TRI_CAP (64 * (WL * (WL + 1) / 2))  // per-fl packed triangle capacity (u64)

typedef unsigned long long u64;
typedef uint32_t u32;

// Wave-local LDS sync (mm: all LDS deps are within one wave).
#define WAVE_SYNC() asm volatile("s_waitcnt lgkmcnt(0)" ::: "memory")

__device__ __forceinline__ u64 shfl64(u64 v, int src) {
  return (u64)__shfl((long long)v, src, 64);
}
__device__ __forceinline__ u64 readlane64(u64 v, int l) {
  u32 lo = (u32)__builtin_amdgcn_readlane((int)(u32)v, l);
  u32 hi = (u32)__builtin_amdgcn_readlane((int)(u32)(v >> 32), l);
  return ((u64)hi << 32) | lo;
}
// Greedy with ISO bulk-accept (R11, verified).
__device__ __forceinline__ u64 greedy64_iso(u64 D, u64 rem, u64 onlyme) {
  u64 lead = 0;
  while (rem) {
    u64 t = D & rem;
    u64 iso = __ballot(t == onlyme) & rem;
    lead |= iso;
    rem &= ~iso;
    if (!rem) break;
    int b = __builtin_ctzll(rem);
    lead |= 1ull << b;
    rem &= ~readlane64(D, b);
    if (!rem) break;
    b = __builtin_ctzll(rem);
    lead |= 1ull << b;
    rem &= ~readlane64(D, b);
  }
  return lead;
}

// ---------------------------------------------------------------------------
// K1 (R13, verified): fused rank + partition-loc + gather/scatter.
// ---------------------------------------------------------------------------
__global__ __launch_bounds__(256) void rg_kernel(
    const float* __restrict__ scores, const float* __restrict__ boxes,
    const int* __restrict__ labels,
    float* __restrict__ sboxes, float* __restrict__ sscore, float* __restrict__ slabel,
    int* __restrict__ lab_slot, int* __restrict__ loc_slot,
    int* __restrict__ pglob,
    float* __restrict__ px1, float* __restrict__ px2, float* __restrict__ py1,
    float* __restrict__ py2, float* __restrict__ parea,
    int* __restrict__ VbufL)
{
  __shared__ u64 keys[NN];                  // 32 KB
  __shared__ int cnt[4][64];
  __shared__ int lcnt[4][64];
  __shared__ int vc[4][3];
  const int f = blockIdx.x >> 6, rb = blockIdx.x & 63;
  const int tid = threadIdx.x, wave = tid >> 6, lane = tid & 63;
  for (int s = 0; s < 16; s++) {
    int idx = tid + 256 * s;
    float sc = scores[f * NN + idx];
    bool valid = sc > 0.2f;                 // COND_THRES
    int lab = labels[f * NN + idx];
    u32 bits = __float_as_uint(sc);
    u32 m = bits ^ ((bits >> 31) ? 0xFFFFFFFFu : 0x80000000u);
    u32 hi = valid ? ~m : 0xFFFFFFFFu;      // smaller = higher score
    u32 lo = ((u32)idx << 2) | (valid ? (u32)lab : 3u);
    keys[idx] = ((u64)hi << 32) | lo;
  }
  __syncthreads();
  if (rb == 0) {                            // per-label totals
    int c0 = 0, c1 = 0, c2 = 0;
    const int base = wave * 1024;
    for (int s = 0; s < 16; s++) {
      u32 lb = (u32)keys[base + s * 64 + lane] & 3u;
      c0 += (lb == 0); c1 += (lb == 1); c2 += (lb == 2);
    }
    for (int off = 32; off; off >>= 1) {
      c0 += __shfl_xor(c0, off, 64);
      c1 += __shfl_xor(c1, off, 64);
      c2 += __shfl_xor(c2, off, 64);
    }
    if (lane == 0) { vc[wave][0] = c0; vc[wave][1] = c1; vc[wave][2] = c2; }
  }
  const int row = rb * 64 + lane;
  const u64 mykey = keys[row];
  const u32 mylab = (u32)mykey & 3u;
  const u64 ltmask = (1ull << lane) - 1ull;
  (void)ltmask;
  int c = 0, lc = 0;
  const int j0 = wave * 1024;
#pragma unroll 8
  for (int j = j0; j < j0 + 1024; j++) {
    u64 kj = keys[j];                       // broadcast LDS read
    bool lt = kj < mykey;
    c += lt ? 1 : 0;
    lc += (lt && (((u32)kj & 3u) == mylab)) ? 1 : 0;
  }
  cnt[wave][lane] = c;
  lcnt[wave][lane] = lc;
  __syncthreads();
  if (rb == 0 && wave == 1 && lane < 3)
    VbufL[f * 3 + lane] = vc[0][lane] + vc[1][lane] + vc[2][lane] + vc[3][lane];
  if (wave == 0) {                          // gather + scatter tail
    int rank = cnt[0][lane] + cnt[1][lane] + cnt[2][lane] + cnt[3][lane];
    int loc  = lcnt[0][lane] + lcnt[1][lane] + lcnt[2][lane] + lcnt[3][lane];
    const int i = row;
    const float* bp = boxes + (size_t)(f * NN + i) * 7;
    float b0 = bp[0], b1v = bp[1], b2v = bp[2], b3 = bp[3], b4 = bp[4], b5 = bp[5], b6 = bp[6];
    int lab = labels[f * NN + i];
    float sc = scores[f * NN + i];
    const int o = f * NN + rank;
    float* sb = sboxes + (size_t)o * 7;
    sb[0] = b0; sb[1] = b1v; sb[2] = b2v; sb[3] = b3; sb[4] = b4; sb[5] = b5; sb[6] = b6;
    sscore[o] = sc;
    slabel[o] = (float)lab;
    if (mylab < 3u) {
      int pi = (f * 3 + (int)mylab) * PL + loc;
      float off = (float)mylab * 10000.0f;  // CLASS_OFFSET
      float cx = b0 + off, cy = b1v;
      float hx = b3 * 0.5f, hy = b4 * 0.5f;
      float x1 = cx - hx, x2 = cx + hx, y1 = cy - hy, y2 = cy + hy;
      float area = (x2 - x1) * (y2 - y1);
      pglob[pi] = rank;
      px1[pi] = x1; px2[pi] = x2; py1[pi] = y1; py2[pi] = y2; parea[pi] = area;
      lab_slot[o] = (int)mylab; loc_slot[o] = loc;
    } else {
      lab_slot[o] = -1; loc_slot[o] = -1;
    }
  }
}

// ---------------------------------------------------------------------------
// Kernel B (R13, verified): per-partition overlap bitmask, two layouts.
// ---------------------------------------------------------------------------
__global__ __launch_bounds__(256) void mask_kernel(
    const float* __restrict__ px1, const float* __restrict__ px2,
    const float* __restrict__ py1, const float* __restrict__ py2,
    const float* __restrict__ parea, const int* __restrict__ pglob,
    const int* __restrict__ VbufL,
    u64* __restrict__ maskP, u64* __restrict__ triT)
{
  __shared__ float4 cbox[1024];
  __shared__ float carea[1024];
  const int bx = blockIdx.x;                // fl*256 + rt*2 + wt
  const int fl = bx >> 8, rem = bx & 255;
  const int rt = rem >> 1, wt = rem & 1;
  const int r0 = rt * 16;
  const int Vl = VbufL[fl];
  if (r0 >= Vl) return;
  if (wt * 1024 >= Vl) return;
  const int tid = threadIdx.x;
  const int ncol = Vl - wt * 1024;
  const int nload = (ncol < 1024) ? ncol : 1024;
  for (int q = tid; q < nload; q += 256) {
    int c = fl * PL + wt * 1024 + q;
    cbox[q] = make_float4(px1[c], px2[c], py1[c], py2[c]);
    carea[q] = parea[c];
  }
  __syncthreads();
  const int row = r0 + (tid & 15);
  const int wl = tid >> 4;
  const int cw = wt * 16 + wl;
  const int nc = Vl - cw * 64;              // valid cols in this word
  if (row >= Vl || nc <= 0) return;
  const int rg = fl * PL + row;
  const float rx1 = px1[rg], rx2 = px2[rg], ry1 = py1[rg], ry2 = py2[rg], ra = parea[rg];
  u64 bits = 0;
  const int qb = wl * 64;
  for (int b = 0; b < 64; b++) {
    float4 cb = cbox[qb + b];
    float ca = carea[qb + b];
    float ix = fminf(rx2, cb.y) - fmaxf(rx1, cb.x);
    ix = fmaxf(ix, 0.0f);
    float iy = fminf(ry2, cb.w) - fmaxf(ry1, cb.z);
    iy = fmaxf(iy, 0.0f);
    float inter = ix * iy;
    float den = fmaxf((ra + ca) - inter, 1e-6f);
    float iou = inter / den;
    bits |= ((u64)(iou > 0.3f)) << b;       // IOU_THRES
  }
  if (nc < 64) bits &= (1ull << nc) - 1ull;
  const int f = fl / 3;
  const int p = pglob[fl * PL + row];
  maskP[((size_t)f * NN + p) * WL + cw] = bits;
  if (row >= 64 * cw) {                     // packed lower triangle
    const int W = (Vl + 63) >> 6;
    int base = 64 * (cw * W - (cw * (cw - 1)) / 2);
    triT[(size_t)fl * TRI_CAP + base + (row - 64 * cw)] = bits;
  }
}

// ---------------------------------------------------------------------------
// Kernel C (R11 core + R17 leader-list compaction). ONE WAVE per (frame,label).
// After leadersP, append compacted {o, fl<<16|loc} entries for mm.
// ---------------------------------------------------------------------------
__global__ __launch_bounds__(64) void nms_kernel(
    const u64* __restrict__ triT, const int* __restrict__ VbufL,
    const int* __restrict__ pglob,
    u64* __restrict__ leadersP, int2* __restrict__ llist, int* __restrict__ lcount)
{
  __shared__ u64 tri[64 * (WF * (WF + 1) / 2) + 128];  // 153.6KB + 1KB slack
  const int fl = blockIdx.x, lane = threadIdx.x;
  const int Vl = VbufL[fl];
  const int W = (Vl + 63) >> 6;
  const u64* mT = triT + (size_t)fl * TRI_CAP;
  const u64 onlyme = 1ull << lane;
  u64 alive = 0;
  if (lane < WL) {
    int rb = Vl - 64 * lane;
    alive = (rb >= 64) ? ~0ull : ((rb > 0) ? ((1ull << rb) - 1ull) : 0ull);
  }
  u64 myLead = 0;

  if (W > 0 && W <= WF) {
    const int totw = 64 * (W * (W + 1) / 2);          // u64 count
    const int nch = (totw * 8 + 1023) >> 10;          // 1KB chunks
    const char* g = (const char*)mT;
    char* l = (char*)tri;
    int batch = 0;
    for (int it = 0; it < nch; it++) {
      __builtin_amdgcn_global_load_lds(
          (const __attribute__((address_space(1))) unsigned int*)(g + (size_t)it * 1024 + (size_t)lane * 16),
          (__attribute__((address_space(3))) unsigned int*)(l + (size_t)it * 1024),
          16, 0, 0);
      if (++batch == 48) {
        asm volatile("s_waitcnt vmcnt(0)" ::: "memory");
        batch = 0;
      }
    }
    asm volatile("s_waitcnt vmcnt(0)" ::: "memory");
    int offw = 0;
    u64 D = tri[lane];                      // diag of block 0
    for (int w = 0; w < W; w++) {
      const int offw_next = offw + 64 * (W - w);
      u64 Dnext = (w + 1 < W) ? tri[offw_next + lane] : 0;  // prefetch
      u64 lead = greedy64_iso(D, readlane64(alive, w), onlyme);
      if (lane == w) myLead = lead;
      if (lead) {
        const u64* strm = tri + offw;
        int v = w + 1;
        for (; v + 3 < W; v += 4) {
          u64 a0 = strm[64 * (v - w) + lane];
          u64 a1 = strm[64 * (v + 1 - w) + lane];
          u64 a2 = strm[64 * (v + 2 - w) + lane];
          u64 a3 = strm[64 * (v + 3 - w) + lane];
          u64 c0 = __ballot((a0 & lead) != 0ull);
          u64 c1 = __ballot((a1 & lead) != 0ull);
          u64 c2 = __ballot((a2 & lead) != 0ull);
          u64 c3 = __ballot((a3 & lead) != 0ull);
          if (lane == v)     alive &= ~c0;
          if (lane == v + 1) alive &= ~c1;
          if (lane == v + 2) alive &= ~c2;
          if (lane == v + 3) alive &= ~c3;
        }
        for (; v < W; v++) {
          u64 a0 = strm[64 * (v - w) + lane];
          u64 c0 = __ballot((a0 & lead) != 0ull);
          if (lane == v) alive &= ~c0;
        }
      }
      D = Dnext;
      offw = offw_next;
    }
  } else if (W > 0) {                       // fallback: global reads
    int offw = 0;
    for (int w = 0; w < W; w++) {
      const u64* strm = mT + offw;
      u64 D = strm[lane];
      u64 lead = greedy64_iso(D, readlane64(alive, w), onlyme);
      if (lane == w) myLead = lead;
      if (lead) {
        for (int v = w + 1; v < W; v++) {
          u64 a0 = strm[64 * (v - w) + lane];
          u64 c0 = __ballot((a0 & lead) != 0ull);
          if (lane == v) alive &= ~c0;
        }
      }
      offw += 64 * (W - w);
    }
  }
  if (lane < WL) leadersP[fl * WL + lane] = myLead;

  // ---- R17: compacted leader list (lane w holds leaders word w) ----
  int nl = __popcll(myLead);
  int incl = nl;
  for (int off = 1; off < 64; off <<= 1) {
    int up = __shfl_up(incl, off, 64);
    if (lane >= off) incl += up;
  }
  int tot = __shfl(incl, 63, 64);
  int base = 0;
  if (lane == 0 && tot > 0) base = atomicAdd(lcount, tot);
  base = __shfl(base, 0, 64);
  int start = base + incl - nl;
  const int f = fl / 3;
  u64 m = myLead;
  while (m) {
    int b = __builtin_ctzll(m);
    m &= m - 1;
    int pos = 64 * lane + b;                // partition-local loc of leader
    int p = pglob[fl * PL + pos];           // global sorted slot
    llist[start] = make_int2(f * NN + p, (fl << 16) | pos);
    start++;
  }
}

// ---------------------------------------------------------------------------
// Kernel D (R13, verified): parallel cid (partition-local). One wave per slot.
// ---------------------------------------------------------------------------
__global__ __launch_bounds__(256) void cid_kernel(
    const u64* __restrict__ maskP, const u64* __restrict__ leadersP,
    const int* __restrict__ lab_slot, const int* __restrict__ loc_slot,
    const int* __restrict__ VbufL, int* __restrict__ cidP)
{
  const int g = blockIdx.x * 4 + (threadIdx.x >> 6);
  const int lane = threadIdx.x & 63;
  const int f = g >> 12, p = g & (NN - 1);
  const int l = lab_slot[f * NN + p];
  if (l < 0) return;
  const int fl = f * 3 + l;
  const int loc = loc_slot[f * NN + p];
  const int Wl = (VbufL[fl] + 63) >> 6;
  u64 L = 0, m = 0;
  if (lane < Wl) {
    L = leadersP[fl * WL + lane];
    m = maskP[((size_t)f * NN + p) * WL + lane];
  }
  const int g6 = loc >> 6, b6 = loc & 63;
  u64 pmask = (lane < g6) ? ~0ull
            : (lane == g6 ? ((b6 == 63) ? ~0ull : ((1ull << (b6 + 1)) - 1ull)) : 0ull);
  u64 v = m & L & pmask;
  u64 bl = __ballot(v != 0ull);
  int cid = -1;
  if (bl != 0ull) {
    int w = __builtin_ctzll(bl);
    u64 vw = shfl64(v, w);
    cid = w * 64 + __builtin_ctzll(vw);
  }
  if (lane == 0) cidP[fl * PL + loc] = cid;
}

// ---------------------------------------------------------------------------
// Kernel E (R17): list-driven members + merge. Grid-stride over the compacted
// leader list only (~3.3k entries vs 16384 rows); non-leader rows are zeroed
// by the bulk hipMemsetAsync on d_out. 4 waves/block, per-wave LDS slices.
// ---------------------------------------------------------------------------
__global__ __launch_bounds__(256) void mm_kernel(
    const int2* __restrict__ llist, const int* __restrict__ lcount,
    const u64* __restrict__ maskP, const int* __restrict__ cidP,
    const int* __restrict__ pglob, const int* __restrict__ VbufL,
    const float* __restrict__ sboxes, const float* __restrict__ sscore,
    const float* __restrict__ slabel,
    const float* __restrict__ W1, const float* __restrict__ b1,
    const float* __restrict__ W2, const float* __restrict__ b2,
    float* __restrict__ out)
{
  __shared__ int   mlistS[4][MAXC];
  __shared__ float mbS[4][MAXC][7];
  __shared__ float lgS[4][MAXC];
  __shared__ float wnS[4][MAXC];
  const int wv = threadIdx.x >> 6, lane = threadIdx.x & 63;
  const u64 ltmask = (1ull << lane) - 1ull;
  int* mlist = mlistS[wv];
  float (*mb)[7] = mbS[wv];
  float* lg = lgS[wv];
  float* wn = wnS[wv];
  float w1r[7];
  for (int d = 0; d < 7; d++) w1r[d] = W1[d * 64 + lane];
  const float b1c = b1[lane], w2c = W2[lane], b2v = b2[0];
  const int cntTot = lcount[0];
  for (int idx = blockIdx.x * 4 + wv; idx < cntTot; idx += 1024) {
    int2 e = llist[idx];
    const int o = e.x;
    const int fl = e.y >> 16, loc = e.y & 0xFFFF;
    const int f = o >> 12;                  // o = f*NN + p, NN = 4096
    float* info = out + (size_t)o * 9;
    float* lead = out + (size_t)BF * NN * 9 + o;
    const u64* mrow = maskP + (size_t)o * WL;
    const int Wl = (VbufL[fl] + 63) >> 6;
    int total = 0;
    for (int w = loc >> 6; w < Wl && total < MAXC; w++) {
      u64 word = mrow[w];
      int pos = w * 64 + lane;
      bool cand = ((word >> lane) & 1ull) && (cidP[fl * PL + pos] == loc);
      u64 mbal = __ballot(cand);
      int r = __popcll(mbal & ltmask);
      int slot = total + r;
      if (cand && slot < MAXC) mlist[slot] = pglob[fl * PL + pos];
      total += __popcll(mbal);
    }
    const int cnt = min(total, MAXC);
    WAVE_SYNC();
    if (lane < cnt) {
      int j = mlist[lane];
      const float* bp = sboxes + (size_t)(f * NN + j) * 7;
      for (int d = 0; d < 7; d++) mb[lane][d] = bp[d];
    }
    WAVE_SYNC();
    for (int s = 0; s < cnt; s++) {
      float t = b1c;
      for (int d = 0; d < 7; d++) t += mb[s][d] * w1r[d];
      float h = fmaxf(t, 0.0f);
      float v = h * w2c;
      for (int off2 = 32; off2 > 0; off2 >>= 1) v += __shfl_xor(v, off2, 64);
      if (lane == 0) lg[s] = v + b2v;
    }
    WAVE_SYNC();
    float mx = -1e30f;
    for (int s = 0; s < cnt; s++) mx = fmaxf(mx, lg[s]);
    float den = 0.0f;
    for (int s = 0; s < cnt; s++) den += expf(lg[s] - mx);
    if (lane < cnt) wn[lane] = expf(lg[lane] - mx) / den;
    WAVE_SYNC();
    float val = 0.0f;
    if (lane < 7) {
      float acc = 0.0f;
      for (int s = 0; s < cnt; s++) acc += wn[s] * mb[s][lane];
      val = acc;
      if (lane >= 3 && lane <= 5 && val <= 0.0f) val = sboxes[(size_t)o * 7 + lane];
    } else if (lane == 7) {
      val = sscore[o];
    } else if (lane == 8) {
      val = slabel[o];
    }
    if (lane < 9) info[lane] = val;
    if (lane == 0) *lead = 1.0f;
    WAVE_SYNC();                            // LDS safe vs next iteration
  }
}

// ---------------------------------------------------------------------------
extern "C" void kernel_launch(void* const* d_in, const int* in_sizes, int n_in,
                              void* d_out, int out_size, void* d_ws, size_t ws_size,
                              hipStream_t stream)
{
  const float* boxes  = (const float*)d_in[0];
  const float* scores = (const float*)d_in[1];
  const int*   labels = (const int*)d_in[2];
  const float* W1     = (const float*)d_in[3];
  const float* b1     = (const float*)d_in[4];
  const float* W2     = (const float*)d_in[5];
  const float* b2     = (const float*)d_in[6];
  float* out = (float*)d_out;

  char* ws = (char*)d_ws;
  size_t off = 0;
  auto alloc = [&](size_t bytes) -> void* {
    void* p = ws + off;
    off = (off + bytes + 255) & ~(size_t)255;
    return p;
  };
  int*   lcount  = (int*)  alloc(256);      // leader-count header (zeroed)
  int2*  llist   = (int2*) alloc((size_t)BF * NN * 8);
  float* sboxes  = (float*)alloc((size_t)BF * NN * 7 * 4);
  float* sscore  = (float*)alloc((size_t)BF * NN * 4);
  float* slabel  = (float*)alloc((size_t)BF * NN * 4);
  int*   lab_slot= (int*)  alloc((size_t)BF * NN * 4);
  int*   loc_slot= (int*)  alloc((size_t)BF * NN * 4);
  int*   pglob   = (int*)  alloc((size_t)BF * 3 * PL * 4);
  float* px1     = (float*)alloc((size_t)BF * 3 * PL * 4);
  float* px2     = (float*)alloc((size_t)BF * 3 * PL * 4);
  float* py1     = (float*)alloc((size_t)BF * 3 * PL * 4);
  float* py2     = (float*)alloc((size_t)BF * 3 * PL * 4);
  float* parea   = (float*)alloc((size_t)BF * 3 * PL * 4);
  int*   VbufL   = (int*)  alloc((size_t)BF * 3 * 4);
  u64*   leadersP= (u64*)  alloc((size_t)BF * 3 * WL * 8);
  int*   cidP    = (int*)  alloc((size_t)BF * 3 * PL * 4);
  u64*   maskP   = (u64*)  alloc((size_t)BF * NN * WL * 8);        // 4 MB
  u64*   triT    = (u64*)  alloc((size_t)BF * 3 * TRI_CAP * 8);    // 3.2 MB
  (void)  alloc(32768);                     // DMA overrun slack after triT

  hipMemsetAsync(lcount, 0, 256, stream);   // zero leader counter
  hipMemsetAsync(d_out, 0, (size_t)out_size * 4, stream);  // bulk-zero output

  rg_kernel<<<BF * 64, 256, 0, stream>>>(scores, boxes, labels, sboxes,
                                         sscore, slabel, lab_slot, loc_slot,
                                         pglob, px1, px2, py1, py2, parea,
                                         VbufL);
  mask_kernel<<<BF * 3 * 256, 256, 0, stream>>>(px1, px2, py1, py2, parea,
                                                pglob, VbufL, maskP, triT);
  nms_kernel<<<BF * 3, 64, 0, stream>>>(triT, VbufL, pglob, leadersP,
                                        llist, lcount);
  cid_kernel<<<BF * NN / 4, 256, 0, stream>>>(maskP, leadersP, lab_slot,
                                              loc_slot, VbufL, cidP);
  mm_kernel<<<256, 256, 0, stream>>>(llist, lcount, maskP, cidP, pglob,
                                     VbufL, sboxes, sscore, slabel,
                                     W1, b1, W2, b2, out);
}

// Round 18
// 179.571 us; speedup vs baseline: 2.4428x; 1.1814x over previous
//
#include <hip/hip_runtime.h>
#include <stdint.h>

// Match numpy reference bit-exactly on the IoU path: no fma contraction.
#pragma clang fp contract(off)

#define BF 4
#define NN 4096
#define MAXC 16
#define PL 2048   // per-label partition capacity
#define WL 32     // PL/64 words per partition row
#define WF 24     // full-LDS leader-pass capacity (Vl<=1536; +15.7 sigma)
#define TRI_CAP (64 * (WL * (WL + 1) / 2))  // per-fl packed triangle capacity (u64)

typedef unsigned long long u64;
typedef uint32_t u32;

// Wave-local LDS sync (mm: all LDS deps are within one wave).
#define WAVE_SYNC() asm volatile("s_waitcnt lgkmcnt(0)" ::: "memory")

__device__ __forceinline__ u64 shfl64(u64 v, int src) {
  return (u64)__shfl((long long)v, src, 64);
}
__device__ __forceinline__ u64 readlane64(u64 v, int l) {
  u32 lo = (u32)__builtin_amdgcn_readlane((int)(u32)v, l);
  u32 hi = (u32)__builtin_amdgcn_readlane((int)(u32)(v >> 32), l);
  return ((u64)hi << 32) | lo;
}
// Greedy with ISO bulk-accept (R11, verified).
__device__ __forceinline__ u64 greedy64_iso(u64 D, u64 rem, u64 onlyme) {
  u64 lead = 0;
  while (rem) {
    u64 t = D & rem;
    u64 iso = __ballot(t == onlyme) & rem;
    lead |= iso;
    rem &= ~iso;
    if (!rem) break;
    int b = __builtin_ctzll(rem);
    lead |= 1ull << b;
    rem &= ~readlane64(D, b);
    if (!rem) break;
    b = __builtin_ctzll(rem);
    lead |= 1ull << b;
    rem &= ~readlane64(D, b);
  }
  return lead;
}

// ---------------------------------------------------------------------------
// K1 (R13, verified): fused rank + partition-loc + gather/scatter.
// ---------------------------------------------------------------------------
__global__ __launch_bounds__(256) void rg_kernel(
    const float* __restrict__ scores, const float* __restrict__ boxes,
    const int* __restrict__ labels,
    float* __restrict__ sboxes, float* __restrict__ sscore, float* __restrict__ slabel,
    int* __restrict__ lab_slot, int* __restrict__ loc_slot,
    int* __restrict__ pglob,
    float* __restrict__ px1, float* __restrict__ px2, float* __restrict__ py1,
    float* __restrict__ py2, float* __restrict__ parea,
    int* __restrict__ VbufL)
{
  __shared__ u64 keys[NN];                  // 32 KB
  __shared__ int cnt[4][64];
  __shared__ int lcnt[4][64];
  __shared__ int vc[4][3];
  const int f = blockIdx.x >> 6, rb = blockIdx.x & 63;
  const int tid = threadIdx.x, wave = tid >> 6, lane = tid & 63;
  for (int s = 0; s < 16; s++) {
    int idx = tid + 256 * s;
    float sc = scores[f * NN + idx];
    bool valid = sc > 0.2f;                 // COND_THRES
    int lab = labels[f * NN + idx];
    u32 bits = __float_as_uint(sc);
    u32 m = bits ^ ((bits >> 31) ? 0xFFFFFFFFu : 0x80000000u);
    u32 hi = valid ? ~m : 0xFFFFFFFFu;      // smaller = higher score
    u32 lo = ((u32)idx << 2) | (valid ? (u32)lab : 3u);
    keys[idx] = ((u64)hi << 32) | lo;
  }
  __syncthreads();
  if (rb == 0) {                            // per-label totals
    int c0 = 0, c1 = 0, c2 = 0;
    const int base = wave * 1024;
    for (int s = 0; s < 16; s++) {
      u32 lb = (u32)keys[base + s * 64 + lane] & 3u;
      c0 += (lb == 0); c1 += (lb == 1); c2 += (lb == 2);
    }
    for (int off = 32; off; off >>= 1) {
      c0 += __shfl_xor(c0, off, 64);
      c1 += __shfl_xor(c1, off, 64);
      c2 += __shfl_xor(c2, off, 64);
    }
    if (lane == 0) { vc[wave][0] = c0; vc[wave][1] = c1; vc[wave][2] = c2; }
  }
  const int row = rb * 64 + lane;
  const u64 mykey = keys[row];
  const u32 mylab = (u32)mykey & 3u;
  int c = 0, lc = 0;
  const int j0 = wave * 1024;
#pragma unroll 8
  for (int j = j0; j < j0 + 1024; j++) {
    u64 kj = keys[j];                       // broadcast LDS read
    bool lt = kj < mykey;
    c += lt ? 1 : 0;
    lc += (lt && (((u32)kj & 3u) == mylab)) ? 1 : 0;
  }
  cnt[wave][lane] = c;
  lcnt[wave][lane] = lc;
  __syncthreads();
  if (rb == 0 && wave == 1 && lane < 3)
    VbufL[f * 3 + lane] = vc[0][lane] + vc[1][lane] + vc[2][lane] + vc[3][lane];
  if (wave == 0) {                          // gather + scatter tail
    int rank = cnt[0][lane] + cnt[1][lane] + cnt[2][lane] + cnt[3][lane];
    int loc  = lcnt[0][lane] + lcnt[1][lane] + lcnt[2][lane] + lcnt[3][lane];
    const int i = row;
    const float* bp = boxes + (size_t)(f * NN + i) * 7;
    float b0 = bp[0], b1v = bp[1], b2v = bp[2], b3 = bp[3], b4 = bp[4], b5 = bp[5], b6 = bp[6];
    int lab = labels[f * NN + i];
    float sc = scores[f * NN + i];
    const int o = f * NN + rank;
    float* sb = sboxes + (size_t)o * 7;
    sb[0] = b0; sb[1] = b1v; sb[2] = b2v; sb[3] = b3; sb[4] = b4; sb[5] = b5; sb[6] = b6;
    sscore[o] = sc;
    slabel[o] = (float)lab;
    if (mylab < 3u) {
      int pi = (f * 3 + (int)mylab) * PL + loc;
      float off = (float)mylab * 10000.0f;  // CLASS_OFFSET
      float cx = b0 + off, cy = b1v;
      float hx = b3 * 0.5f, hy = b4 * 0.5f;
      float x1 = cx - hx, x2 = cx + hx, y1 = cy - hy, y2 = cy + hy;
      float area = (x2 - x1) * (y2 - y1);
      pglob[pi] = rank;
      px1[pi] = x1; px2[pi] = x2; py1[pi] = y1; py2[pi] = y2; parea[pi] = area;
      lab_slot[o] = (int)mylab; loc_slot[o] = loc;
    } else {
      lab_slot[o] = -1; loc_slot[o] = -1;
    }
  }
}

// ---------------------------------------------------------------------------
// Kernel B (R13, verified): per-partition overlap bitmask, two layouts.
// ---------------------------------------------------------------------------
__global__ __launch_bounds__(256) void mask_kernel(
    const float* __restrict__ px1, const float* __restrict__ px2,
    const float* __restrict__ py1, const float* __restrict__ py2,
    const float* __restrict__ parea, const int* __restrict__ pglob,
    const int* __restrict__ VbufL,
    u64* __restrict__ maskP, u64* __restrict__ triT)
{
  __shared__ float4 cbox[1024];
  __shared__ float carea[1024];
  const int bx = blockIdx.x;                // fl*256 + rt*2 + wt
  const int fl = bx >> 8, rem = bx & 255;
  const int rt = rem >> 1, wt = rem & 1;
  const int r0 = rt * 16;
  const int Vl = VbufL[fl];
  if (r0 >= Vl) return;
  if (wt * 1024 >= Vl) return;
  const int tid = threadIdx.x;
  const int ncol = Vl - wt * 1024;
  const int nload = (ncol < 1024) ? ncol : 1024;
  for (int q = tid; q < nload; q += 256) {
    int c = fl * PL + wt * 1024 + q;
    cbox[q] = make_float4(px1[c], px2[c], py1[c], py2[c]);
    carea[q] = parea[c];
  }
  __syncthreads();
  const int row = r0 + (tid & 15);
  const int wl = tid >> 4;
  const int cw = wt * 16 + wl;
  const int nc = Vl - cw * 64;              // valid cols in this word
  if (row >= Vl || nc <= 0) return;
  const int rg = fl * PL + row;
  const float rx1 = px1[rg], rx2 = px2[rg], ry1 = py1[rg], ry2 = py2[rg], ra = parea[rg];
  u64 bits = 0;
  const int qb = wl * 64;
  for (int b = 0; b < 64; b++) {
    float4 cb = cbox[qb + b];
    float ca = carea[qb + b];
    float ix = fminf(rx2, cb.y) - fmaxf(rx1, cb.x);
    ix = fmaxf(ix, 0.0f);
    float iy = fminf(ry2, cb.w) - fmaxf(ry1, cb.z);
    iy = fmaxf(iy, 0.0f);
    float inter = ix * iy;
    float den = fmaxf((ra + ca) - inter, 1e-6f);
    float iou = inter / den;
    bits |= ((u64)(iou > 0.3f)) << b;       // IOU_THRES
  }
  if (nc < 64) bits &= (1ull << nc) - 1ull;
  const int f = fl / 3;
  const int p = pglob[fl * PL + row];
  maskP[((size_t)f * NN + p) * WL + cw] = bits;
  if (row >= 64 * cw) {                     // packed lower triangle
    const int W = (Vl + 63) >> 6;
    int base = 64 * (cw * W - (cw * (cw - 1)) / 2);
    triT[(size_t)fl * TRI_CAP + base + (row - 64 * cw)] = bits;
  }
}

// ---------------------------------------------------------------------------
// Kernel C (R11 core + R17 leader-list compaction, verified).
// ---------------------------------------------------------------------------
__global__ __launch_bounds__(64) void nms_kernel(
    const u64* __restrict__ triT, const int* __restrict__ VbufL,
    const int* __restrict__ pglob,
    u64* __restrict__ leadersP, int2* __restrict__ llist, int* __restrict__ lcount)
{
  __shared__ u64 tri[64 * (WF * (WF + 1) / 2) + 128];  // 153.6KB + 1KB slack
  const int fl = blockIdx.x, lane = threadIdx.x;
  const int Vl = VbufL[fl];
  const int W = (Vl + 63) >> 6;
  const u64* mT = triT + (size_t)fl * TRI_CAP;
  const u64 onlyme = 1ull << lane;
  u64 alive = 0;
  if (lane < WL) {
    int rb = Vl - 64 * lane;
    alive = (rb >= 64) ? ~0ull : ((rb > 0) ? ((1ull << rb) - 1ull) : 0ull);
  }
  u64 myLead = 0;

  if (W > 0 && W <= WF) {
    const int totw = 64 * (W * (W + 1) / 2);          // u64 count
    const int nch = (totw * 8 + 1023) >> 10;          // 1KB chunks
    const char* g = (const char*)mT;
    char* l = (char*)tri;
    int batch = 0;
    for (int it = 0; it < nch; it++) {
      __builtin_amdgcn_global_load_lds(
          (const __attribute__((address_space(1))) unsigned int*)(g + (size_t)it * 1024 + (size_t)lane * 16),
          (__attribute__((address_space(3))) unsigned int*)(l + (size_t)it * 1024),
          16, 0, 0);
      if (++batch == 48) {
        asm volatile("s_waitcnt vmcnt(0)" ::: "memory");
        batch = 0;
      }
    }
    asm volatile("s_waitcnt vmcnt(0)" ::: "memory");
    int offw = 0;
    u64 D = tri[lane];                      // diag of block 0
    for (int w = 0; w < W; w++) {
      const int offw_next = offw + 64 * (W - w);
      u64 Dnext = (w + 1 < W) ? tri[offw_next + lane] : 0;  // prefetch
      u64 lead = greedy64_iso(D, readlane64(alive, w), onlyme);
      if (lane == w) myLead = lead;
      if (lead) {
        const u64* strm = tri + offw;
        int v = w + 1;
        for (; v + 3 < W; v += 4) {
          u64 a0 = strm[64 * (v - w) + lane];
          u64 a1 = strm[64 * (v + 1 - w) + lane];
          u64 a2 = strm[64 * (v + 2 - w) + lane];
          u64 a3 = strm[64 * (v + 3 - w) + lane];
          u64 c0 = __ballot((a0 & lead) != 0ull);
          u64 c1 = __ballot((a1 & lead) != 0ull);
          u64 c2 = __ballot((a2 & lead) != 0ull);
          u64 c3 = __ballot((a3 & lead) != 0ull);
          if (lane == v)     alive &= ~c0;
          if (lane == v + 1) alive &= ~c1;
          if (lane == v + 2) alive &= ~c2;
          if (lane == v + 3) alive &= ~c3;
        }
        for (; v < W; v++) {
          u64 a0 = strm[64 * (v - w) + lane];
          u64 c0 = __ballot((a0 & lead) != 0ull);
          if (lane == v) alive &= ~c0;
        }
      }
      D = Dnext;
      offw = offw_next;
    }
  } else if (W > 0) {                       // fallback: global reads
    int offw = 0;
    for (int w = 0; w < W; w++) {
      const u64* strm = mT + offw;
      u64 D = strm[lane];
      u64 lead = greedy64_iso(D, readlane64(alive, w), onlyme);
      if (lane == w) myLead = lead;
      if (lead) {
        for (int v = w + 1; v < W; v++) {
          u64 a0 = strm[64 * (v - w) + lane];
          u64 c0 = __ballot((a0 & lead) != 0ull);
          if (lane == v) alive &= ~c0;
        }
      }
      offw += 64 * (W - w);
    }
  }
  if (lane < WL) leadersP[fl * WL + lane] = myLead;

  // compacted leader list (lane w holds leaders word w)
  int nl = __popcll(myLead);
  int incl = nl;
  for (int off = 1; off < 64; off <<= 1) {
    int up = __shfl_up(incl, off, 64);
    if (lane >= off) incl += up;
  }
  int tot = __shfl(incl, 63, 64);
  int base = 0;
  if (lane == 0 && tot > 0) base = atomicAdd(lcount, tot);
  base = __shfl(base, 0, 64);
  int start = base + incl - nl;
  const int f = fl / 3;
  u64 m = myLead;
  while (m) {
    int b = __builtin_ctzll(m);
    m &= m - 1;
    int pos = 64 * lane + b;                // partition-local loc of leader
    int p = pglob[fl * PL + pos];           // global sorted slot
    llist[start] = make_int2(f * NN + p, (fl << 16) | pos);
    start++;
  }
}

// ---------------------------------------------------------------------------
// Kernel D (R13, verified): parallel cid (partition-local). One wave per slot.
// ---------------------------------------------------------------------------
__global__ __launch_bounds__(256) void cid_kernel(
    const u64* __restrict__ maskP, const u64* __restrict__ leadersP,
    const int* __restrict__ lab_slot, const int* __restrict__ loc_slot,
    const int* __restrict__ VbufL, int* __restrict__ cidP)
{
  const int g = blockIdx.x * 4 + (threadIdx.x >> 6);
  const int lane = threadIdx.x & 63;
  const int f = g >> 12, p = g & (NN - 1);
  const int l = lab_slot[f * NN + p];
  if (l < 0) return;
  const int fl = f * 3 + l;
  const int loc = loc_slot[f * NN + p];
  const int Wl = (VbufL[fl] + 63) >> 6;
  u64 L = 0, m = 0;
  if (lane < Wl) {
    L = leadersP[fl * WL + lane];
    m = maskP[((size_t)f * NN + p) * WL + lane];
  }
  const int g6 = loc >> 6, b6 = loc & 63;
  u64 pmask = (lane < g6) ? ~0ull
            : (lane == g6 ? ((b6 == 63) ? ~0ull : ((1ull << (b6 + 1)) - 1ull)) : 0ull);
  u64 v = m & L & pmask;
  u64 bl = __ballot(v != 0ull);
  int cid = -1;
  if (bl != 0ull) {
    int w = __builtin_ctzll(bl);
    u64 vw = shfl64(v, w);
    cid = w * 64 + __builtin_ctzll(vw);
  }
  if (lane == 0) cidP[fl * PL + loc] = cid;
}

// ---------------------------------------------------------------------------
// Kernel E (R18): list-driven members + merge, one leader per wave, 4096
// waves (13 active waves/CU at ~3.3k leaders). Members scan is a COUNTED
// loop (no total<MAXC early-exit; provably identical output: writes guarded
// by slot<MAXC, min(total,MAXC) unchanged) -> compiler pipelines all word
// loads -> one exposed latency instead of ~9 (R17's 61us was this chain at
// 4 waves/CU).
// ---------------------------------------------------------------------------
__global__ __launch_bounds__(256) void mm_kernel(
    const int2* __restrict__ llist, const int* __restrict__ lcount,
    const u64* __restrict__ maskP, const int* __restrict__ cidP,
    const int* __restrict__ pglob, const int* __restrict__ VbufL,
    const float* __restrict__ sboxes, const float* __restrict__ sscore,
    const float* __restrict__ slabel,
    const float* __restrict__ W1, const float* __restrict__ b1,
    const float* __restrict__ W2, const float* __restrict__ b2,
    float* __restrict__ out)
{
  __shared__ int   mlistS[4][MAXC];
  __shared__ float mbS[4][MAXC][7];
  __shared__ float lgS[4][MAXC];
  __shared__ float wnS[4][MAXC];
  const int wv = threadIdx.x >> 6, lane = threadIdx.x & 63;
  const u64 ltmask = (1ull << lane) - 1ull;
  int* mlist = mlistS[wv];
  float (*mb)[7] = mbS[wv];
  float* lg = lgS[wv];
  float* wn = wnS[wv];
  float w1r[7];
  for (int d = 0; d < 7; d++) w1r[d] = W1[d * 64 + lane];
  const float b1c = b1[lane], w2c = W2[lane], b2v = b2[0];
  const int cntTot = lcount[0];
  for (int idx = blockIdx.x * 4 + wv; idx < cntTot; idx += 4096) {
    int2 e = llist[idx];
    const int o = e.x;
    const int fl = e.y >> 16, loc = e.y & 0xFFFF;
    const int f = o >> 12;                  // o = f*NN + p, NN = 4096
    float* info = out + (size_t)o * 9;
    float* lead = out + (size_t)BF * NN * 9 + o;
    const u64* mrow = maskP + (size_t)o * WL;
    const int Wl = (VbufL[fl] + 63) >> 6;
    const int w0 = loc >> 6;
    int total = 0;
    for (int w = w0; w < Wl; w++) {         // counted loop: loads pipeline
      u64 word = mrow[w];
      int pos = w * 64 + lane;
      bool cand = ((word >> lane) & 1ull) && (cidP[fl * PL + pos] == loc);
      u64 mbal = __ballot(cand);
      int r = __popcll(mbal & ltmask);
      int slot = total + r;
      if (cand && slot < MAXC) mlist[slot] = pglob[fl * PL + pos];
      total += __popcll(mbal);
    }
    const int cnt = min(total, MAXC);
    WAVE_SYNC();
    if (lane < cnt) {
      int j = mlist[lane];
      const float* bp = sboxes + (size_t)(f * NN + j) * 7;
      for (int d = 0; d < 7; d++) mb[lane][d] = bp[d];
    }
    WAVE_SYNC();
    for (int s = 0; s < cnt; s++) {
      float t = b1c;
      for (int d = 0; d < 7; d++) t += mb[s][d] * w1r[d];
      float h = fmaxf(t, 0.0f);
      float v = h * w2c;
      for (int off2 = 32; off2 > 0; off2 >>= 1) v += __shfl_xor(v, off2, 64);
      if (lane == 0) lg[s] = v + b2v;
    }
    WAVE_SYNC();
    float mx = -1e30f;
    for (int s = 0; s < cnt; s++) mx = fmaxf(mx, lg[s]);
    float den = 0.0f;
    for (int s = 0; s < cnt; s++) den += expf(lg[s] - mx);
    if (lane < cnt) wn[lane] = expf(lg[lane] - mx) / den;
    WAVE_SYNC();
    float val = 0.0f;
    if (lane < 7) {
      float acc = 0.0f;
      for (int s = 0; s < cnt; s++) acc += wn[s] * mb[s][lane];
      val = acc;
      if (lane >= 3 && lane <= 5 && val <= 0.0f) val = sboxes[(size_t)o * 7 + lane];
    } else if (lane == 7) {
      val = sscore[o];
    } else if (lane == 8) {
      val = slabel[o];
    }
    if (lane < 9) info[lane] = val;
    if (lane == 0) *lead = 1.0f;
    WAVE_SYNC();                            // LDS safe vs next iteration
  }
}

// ---------------------------------------------------------------------------
extern "C" void kernel_launch(void* const* d_in, const int* in_sizes, int n_in,
                              void* d_out, int out_size, void* d_ws, size_t ws_size,
                              hipStream_t stream)
{
  const float* boxes  = (const float*)d_in[0];
  const float* scores = (const float*)d_in[1];
  const int*   labels = (const int*)d_in[2];
  const float* W1     = (const float*)d_in[3];
  const float* b1     = (const float*)d_in[4];
  const float* W2     = (const float*)d_in[5];
  const float* b2     = (const float*)d_in[6];
  float* out = (float*)d_out;

  char* ws = (char*)d_ws;
  size_t off = 0;
  auto alloc = [&](size_t bytes) -> void* {
    void* p = ws + off;
    off = (off + bytes + 255) & ~(size_t)255;
    return p;
  };
  int*   lcount  = (int*)  alloc(256);      // leader-count header (zeroed)
  int2*  llist   = (int2*) alloc((size_t)BF * NN * 8);
  float* sboxes  = (float*)alloc((size_t)BF * NN * 7 * 4);
  float* sscore  = (float*)alloc((size_t)BF * NN * 4);
  float* slabel  = (float*)alloc((size_t)BF * NN * 4);
  int*   lab_slot= (int*)  alloc((size_t)BF * NN * 4);
  int*   loc_slot= (int*)  alloc((size_t)BF * NN * 4);
  int*   pglob   = (int*)  alloc((size_t)BF * 3 * PL * 4);
  float* px1     = (float*)alloc((size_t)BF * 3 * PL * 4);
  float* px2     = (float*)alloc((size_t)BF * 3 * PL * 4);
  float* py1     = (float*)alloc((size_t)BF * 3 * PL * 4);
  float* py2     = (float*)alloc((size_t)BF * 3 * PL * 4);
  float* parea   = (float*)alloc((size_t)BF * 3 * PL * 4);
  int*   VbufL   = (int*)  alloc((size_t)BF * 3 * 4);
  u64*   leadersP= (u64*)  alloc((size_t)BF * 3 * WL * 8);
  int*   cidP    = (int*)  alloc((size_t)BF * 3 * PL * 4);
  u64*   maskP   = (u64*)  alloc((size_t)BF * NN * WL * 8);        // 4 MB
  u64*   triT    = (u64*)  alloc((size_t)BF * 3 * TRI_CAP * 8);    // 3.2 MB
  (void)  alloc(32768);                     // DMA overrun slack after triT

  hipMemsetAsync(lcount, 0, 256, stream);   // zero leader counter
  hipMemsetAsync(d_out, 0, (size_t)out_size * 4, stream);  // bulk-zero output

  rg_kernel<<<BF * 64, 256, 0, stream>>>(scores, boxes, labels, sboxes,
                                         sscore, slabel, lab_slot, loc_slot,
                                         pglob, px1, px2, py1, py2, parea,
                                         VbufL);
  mask_kernel<<<BF * 3 * 256, 256, 0, stream>>>(px1, px2, py1, py2, parea,
                                                pglob, VbufL, maskP, triT);
  nms_kernel<<<BF * 3, 64, 0, stream>>>(triT, VbufL, pglob, leadersP,
                                        llist, lcount);
  cid_kernel<<<BF * NN / 4, 256, 0, stream>>>(maskP, leadersP, lab_slot,
                                              loc_slot, VbufL, cidP);
  mm_kernel<<<1024, 256, 0, stream>>>(llist, lcount, maskP, cidP, pglob,
                                      VbufL, sboxes, sscore, slabel,
                                      W1, b1, W2, b2, out);
}